// Round 1
// baseline (514.937 us; speedup 1.0000x reference)
//
#include <hip/hip_runtime.h>

// ---------------------------------------------------------------------------
// MultiSourceGNNBlock: two independent 2-layer GAT stacks on shared input.
// N_nodes = 8000, dims: layer0 64->256 (4 heads x 64), layer1 256->256.
// Strategy: dst-CSR build (no float atomics), fused GEMM+alpha, per-dst
// online-softmax gather-aggregate.
// ---------------------------------------------------------------------------

#define NEG_SLOPE 0.2f

// ---------------- CSR build ----------------

__global__ __launch_bounds__(256) void count_kernel(const int* __restrict__ ei,
                                                    int E_raw, int N,
                                                    int* __restrict__ cnt) {
    int i = blockIdx.x * 256 + threadIdx.x;
    int tot = E_raw + N;
    if (i >= tot) return;
    int dst = (i < E_raw) ? ei[E_raw + i] : (i - E_raw);  // row 1 = dst; tail = self-loops
    atomicAdd(&cnt[dst], 1);
}

__global__ __launch_bounds__(1024) void scan_kernel(const int* __restrict__ cnt,
                                                    int* __restrict__ rowptr, int n) {
    __shared__ int buf[1024];
    int tid = threadIdx.x;
    if (tid == 0) rowptr[0] = 0;
    int base = 0;
    for (int chunk = 0; chunk < n; chunk += 1024) {
        int i = chunk + tid;
        int v = (i < n) ? cnt[i] : 0;
        buf[tid] = v;
        __syncthreads();
        for (int off = 1; off < 1024; off <<= 1) {
            int t = (tid >= off) ? buf[tid - off] : 0;
            __syncthreads();
            buf[tid] += t;
            __syncthreads();
        }
        if (i < n) rowptr[i + 1] = base + buf[tid];
        base += buf[1023];
        __syncthreads();  // buf stable before next chunk overwrites
    }
}

__global__ __launch_bounds__(256) void scatter_kernel(const int* __restrict__ ei,
                                                      int E_raw, int N,
                                                      const int* __restrict__ rowptr,
                                                      int* __restrict__ cur,
                                                      int* __restrict__ csr) {
    int i = blockIdx.x * 256 + threadIdx.x;
    int tot = E_raw + N;
    if (i >= tot) return;
    int src, dst;
    if (i < E_raw) { src = ei[i]; dst = ei[E_raw + i]; }
    else           { src = dst = i - E_raw; }
    int pos = rowptr[dst] + atomicAdd(&cur[dst], 1);
    csr[pos] = src;
}

// ---------------- fused GEMM (xh = h @ W) + alpha_src/alpha_dst ----------------
// h: [M,K], W: [K,256], xh: [M,256]. alS/alD: [M,4].
// Block: 256 threads, 32 rows/block. Thread tid owns output column tid.
// head = tid>>6; the per-head 64-dim alpha dot reduces over exactly one wave.

__global__ __launch_bounds__(256) void gemm_alpha_kernel(
        const float* __restrict__ h, const float* __restrict__ W,
        const float* __restrict__ a_src, const float* __restrict__ a_dst,
        float* __restrict__ xh, float* __restrict__ alS, float* __restrict__ alD,
        int K, int M) {
    __shared__ float hs[32 * 256];  // 32KB max (K<=256)
    int tid = threadIdx.x;
    int row0 = blockIdx.x * 32;

    // stage 32 contiguous rows of h: 32*K contiguous floats
    int tileElems = 32 * K;
    int gbase = row0 * K;
    int glimit = M * K;
    for (int idx = tid; idx < tileElems; idx += 256) {
        int g = gbase + idx;
        hs[idx] = (g < glimit) ? h[g] : 0.f;
    }
    __syncthreads();

    float acc[32];
#pragma unroll
    for (int r = 0; r < 32; r++) acc[r] = 0.f;

    for (int k = 0; k < K; k += 4) {
        float w0 = W[(k + 0) * 256 + tid];
        float w1 = W[(k + 1) * 256 + tid];
        float w2 = W[(k + 2) * 256 + tid];
        float w3 = W[(k + 3) * 256 + tid];
#pragma unroll
        for (int r = 0; r < 32; r++) {
            float4 hv = *reinterpret_cast<const float4*>(&hs[r * K + k]);
            acc[r] += hv.x * w0 + hv.y * w1 + hv.z * w2 + hv.w * w3;
        }
    }

    float asw = a_src[tid];  // a_src is [4,64] flat = 256
    float adw = a_dst[tid];
    int head = tid >> 6;
#pragma unroll
    for (int r = 0; r < 32; r++) {
        int row = row0 + r;
        if (row >= M) break;
        float v = acc[r];
        xh[row * 256 + tid] = v;
        float s1 = v * asw;
        float s2 = v * adw;
#pragma unroll
        for (int off = 32; off >= 1; off >>= 1) {
            s1 += __shfl_xor(s1, off);
            s2 += __shfl_xor(s2, off);
        }
        if ((tid & 63) == 0) {
            alS[row * 4 + head] = s1;
            alD[row * 4 + head] = s2;
        }
    }
}

// ---------------- per-destination online-softmax aggregation ----------------
// Block = one dst node; 256 threads = (head = tid>>6, dim = tid&63).

__global__ __launch_bounds__(256) void attn_kernel(
        const int* __restrict__ rowptr, const int* __restrict__ csr,
        const float* __restrict__ xh, const float* __restrict__ alS,
        const float* __restrict__ alD, const float* __restrict__ bias,
        float* __restrict__ out, int do_relu) {
    int dst = blockIdx.x;
    int tid = threadIdx.x;
    int head = tid >> 6;
    int beg = rowptr[dst], end = rowptr[dst + 1];
    float ad = alD[dst * 4 + head];

    float m = -1e30f, den = 0.f, acc = 0.f;
    for (int i = beg; i < end; i++) {
        int s = csr[i];
        float e = alS[s * 4 + head] + ad;
        e = (e > 0.f) ? e : NEG_SLOPE * e;
        float mnew = fmaxf(m, e);
        float sc = __expf(m - mnew);   // 0 on first iter (m=-1e30)
        float p  = __expf(e - mnew);
        den = den * sc + p;
        acc = acc * sc + p * xh[s * 256 + tid];
        m = mnew;
    }
    float o = acc / (den + 1e-16f) + bias[tid];
    if (do_relu) o = fmaxf(o, 0.f);
    out[dst * 256 + tid] = o;
}

// ---------------------------------------------------------------------------

extern "C" void kernel_launch(void* const* d_in, const int* in_sizes, int n_in,
                              void* d_out, int out_size, void* d_ws, size_t ws_size,
                              hipStream_t stream) {
    const float* h0  = (const float*)d_in[0];
    const int*   ei1 = (const int*)d_in[1];
    const int*   ei2 = (const int*)d_in[2];
    // per-source weights: W, a_src, a_dst, b  x 2 layers
    const float* W10  = (const float*)d_in[3];
    const float* as10 = (const float*)d_in[4];
    const float* ad10 = (const float*)d_in[5];
    const float* b10  = (const float*)d_in[6];
    const float* W11  = (const float*)d_in[7];
    const float* as11 = (const float*)d_in[8];
    const float* ad11 = (const float*)d_in[9];
    const float* b11  = (const float*)d_in[10];
    const float* W20  = (const float*)d_in[11];
    const float* as20 = (const float*)d_in[12];
    const float* ad20 = (const float*)d_in[13];
    const float* b20  = (const float*)d_in[14];
    const float* W21  = (const float*)d_in[15];
    const float* as21 = (const float*)d_in[16];
    const float* ad21 = (const float*)d_in[17];
    const float* b21  = (const float*)d_in[18];

    const int N  = in_sizes[0] / 64;   // 8000 nodes
    const int E1 = in_sizes[1] / 2;    // raw edges source 1
    const int E2 = in_sizes[2] / 2;

    // ---- workspace carve (256B aligned) ----
    char* base = (char*)d_ws;
    size_t off = 0;
    auto carve = [&](size_t bytes) -> void* {
        void* p = base + off;
        off += (bytes + 255) & ~(size_t)255;
        return p;
    };
    int* rowptr1 = (int*)carve((size_t)(N + 1) * 4);
    int* csr1    = (int*)carve((size_t)(E1 + N) * 4);
    int* rowptr2 = (int*)carve((size_t)(N + 1) * 4);
    int* csr2    = (int*)carve((size_t)(E2 + N) * 4);
    int* cnt     = (int*)carve((size_t)N * 4);
    float* xh    = (float*)carve((size_t)N * 256 * 4);
    float* hbuf  = (float*)carve((size_t)N * 256 * 4);
    float* alS   = (float*)carve((size_t)N * 4 * 4);
    float* alD   = (float*)carve((size_t)N * 4 * 4);
    (void)ws_size; (void)n_in;

    // ---- CSR build for both edge sets ----
    auto build_csr = [&](const int* ei, int E_raw, int* rowptr, int* csr) {
        int tot = E_raw + N;
        int blocks = (tot + 255) / 256;
        hipMemsetAsync(cnt, 0, (size_t)N * 4, stream);
        count_kernel<<<blocks, 256, 0, stream>>>(ei, E_raw, N, cnt);
        scan_kernel<<<1, 1024, 0, stream>>>(cnt, rowptr, N);
        hipMemsetAsync(cnt, 0, (size_t)N * 4, stream);
        scatter_kernel<<<blocks, 256, 0, stream>>>(ei, E_raw, N, rowptr, cnt, csr);
    };
    build_csr(ei1, E1, rowptr1, csr1);
    build_csr(ei2, E2, rowptr2, csr2);

    const int gemmBlocks = (N + 31) / 32;
    float* out0 = (float*)d_out;
    float* out1 = (float*)d_out + (size_t)N * 256;

    // ---- source pipeline: layer0 (relu) -> layer1 ----
    auto run_source = [&](const int* rowptr, const int* csr,
                          const float* W0, const float* aS0, const float* aD0, const float* bb0,
                          const float* W1, const float* aS1, const float* aD1, const float* bb1,
                          float* out) {
        gemm_alpha_kernel<<<gemmBlocks, 256, 0, stream>>>(h0, W0, aS0, aD0, xh, alS, alD, 64, N);
        attn_kernel<<<N, 256, 0, stream>>>(rowptr, csr, xh, alS, alD, bb0, hbuf, 1);
        gemm_alpha_kernel<<<gemmBlocks, 256, 0, stream>>>(hbuf, W1, aS1, aD1, xh, alS, alD, 256, N);
        attn_kernel<<<N, 256, 0, stream>>>(rowptr, csr, xh, alS, alD, bb1, out, 0);
    };
    run_source(rowptr1, csr1, W10, as10, ad10, b10, W11, as11, ad11, b11, out0);
    run_source(rowptr2, csr2, W20, as20, ad20, b20, W21, as21, ad21, b21, out1);
}

// Round 2
// 269.585 us; speedup vs baseline: 1.9101x; 1.9101x over previous
//
#include <hip/hip_runtime.h>

// ---------------------------------------------------------------------------
// MultiSourceGNNBlock: two independent 2-layer GAT stacks on shared input.
// N_nodes = 8000, dims: layer0 64->256 (4 heads x 64), layer1 256->256.
// R1: tiled 64x64 GEMM (500 blocks), wave-parallel two-phase softmax attn,
// single-pass scan.
// ---------------------------------------------------------------------------

#define NEG_SLOPE 0.2f

// ---------------- CSR build ----------------

__global__ __launch_bounds__(256) void count_kernel(const int* __restrict__ ei,
                                                    int E_raw, int N,
                                                    int* __restrict__ cnt) {
    int i = blockIdx.x * 256 + threadIdx.x;
    int tot = E_raw + N;
    if (i >= tot) return;
    int dst = (i < E_raw) ? ei[E_raw + i] : (i - E_raw);  // row 1 = dst; tail = self-loops
    atomicAdd(&cnt[dst], 1);
}

// single-pass exclusive scan for n <= 8192
__global__ __launch_bounds__(1024) void scan_kernel(const int* __restrict__ cnt,
                                                    int* __restrict__ rowptr, int n) {
    __shared__ int buf[1024];
    int tid = threadIdx.x;
    int v[8];
    int local = 0;
    int base = tid * 8;
#pragma unroll
    for (int j = 0; j < 8; j++) {
        int i = base + j;
        int x = (i < n) ? cnt[i] : 0;
        v[j] = local;          // exclusive prefix within thread
        local += x;
    }
    buf[tid] = local;
    __syncthreads();
    for (int off = 1; off < 1024; off <<= 1) {
        int t = (tid >= off) ? buf[tid - off] : 0;
        __syncthreads();
        buf[tid] += t;
        __syncthreads();
    }
    int prev = (tid == 0) ? 0 : buf[tid - 1];
#pragma unroll
    for (int j = 0; j < 8; j++) {
        int i = base + j;
        if (i < n) rowptr[i] = prev + v[j];
    }
    if (tid == 1023) rowptr[n] = buf[1023];
}

__global__ __launch_bounds__(256) void scatter_kernel(const int* __restrict__ ei,
                                                      int E_raw, int N,
                                                      const int* __restrict__ rowptr,
                                                      int* __restrict__ cur,
                                                      int* __restrict__ csr) {
    int i = blockIdx.x * 256 + threadIdx.x;
    int tot = E_raw + N;
    if (i >= tot) return;
    int src, dst;
    if (i < E_raw) { src = ei[i]; dst = ei[E_raw + i]; }
    else           { src = dst = i - E_raw; }
    int pos = rowptr[dst] + atomicAdd(&cur[dst], 1);
    csr[pos] = src;
}

// ---------------- tiled GEMM (xh = h @ W) + fused alpha ----------------
// h: [M,K], W: [K,256]. Block tile 64 rows x 64 cols; col-block == head.
// 256 threads: tc = tid&15 (col group of 4), tr = tid>>4 (row group of 4).
// A staged transposed (As[k][row]) so both fragment reads are float4.

#define KT 16

__global__ __launch_bounds__(256) void gemm_alpha_kernel(
        const float* __restrict__ h, const float* __restrict__ W,
        const float* __restrict__ a_src, const float* __restrict__ a_dst,
        float* __restrict__ xh, float* __restrict__ alS, float* __restrict__ alD,
        int K, int M) {
    __shared__ float As[KT][64];
    __shared__ float Bs[KT][64];
    int tid = threadIdx.x;
    int row0 = blockIdx.x * 64;
    int head = blockIdx.y;
    int c0 = head * 64;
    int tc = tid & 15, tr = tid >> 4;

    float acc[4][4] = {};

    int arow = tid >> 2, aseg = tid & 3;   // A stage: 64 rows x (4 x float4) of KT
    int brow = tid >> 4, bseg = tid & 15;  // B stage: KT rows x (16 x float4) of 64

    const float* hA = &h[(size_t)(row0 + arow) * K + aseg * 4];
    const float* wB = &W[(size_t)brow * 256 + c0 + bseg * 4];

    for (int k0 = 0; k0 < K; k0 += KT) {
        float4 av = *(const float4*)(hA + k0);
        float4 bv = *(const float4*)(wB + (size_t)k0 * 256);
        __syncthreads();
        As[aseg * 4 + 0][arow] = av.x;
        As[aseg * 4 + 1][arow] = av.y;
        As[aseg * 4 + 2][arow] = av.z;
        As[aseg * 4 + 3][arow] = av.w;
        *(float4*)&Bs[brow][bseg * 4] = bv;
        __syncthreads();
#pragma unroll
        for (int kk = 0; kk < KT; kk++) {
            float4 a = *(const float4*)&As[kk][tr * 4];
            float4 b = *(const float4*)&Bs[kk][tc * 4];
            acc[0][0] += a.x * b.x; acc[0][1] += a.x * b.y; acc[0][2] += a.x * b.z; acc[0][3] += a.x * b.w;
            acc[1][0] += a.y * b.x; acc[1][1] += a.y * b.y; acc[1][2] += a.y * b.z; acc[1][3] += a.y * b.w;
            acc[2][0] += a.z * b.x; acc[2][1] += a.z * b.y; acc[2][2] += a.z * b.z; acc[2][3] += a.z * b.w;
            acc[3][0] += a.w * b.x; acc[3][1] += a.w * b.y; acc[3][2] += a.w * b.z; acc[3][3] += a.w * b.w;
        }
    }

    float asw0 = a_src[c0 + tc * 4 + 0], asw1 = a_src[c0 + tc * 4 + 1];
    float asw2 = a_src[c0 + tc * 4 + 2], asw3 = a_src[c0 + tc * 4 + 3];
    float adw0 = a_dst[c0 + tc * 4 + 0], adw1 = a_dst[c0 + tc * 4 + 1];
    float adw2 = a_dst[c0 + tc * 4 + 2], adw3 = a_dst[c0 + tc * 4 + 3];

#pragma unroll
    for (int i = 0; i < 4; i++) {
        int row = row0 + tr * 4 + i;
        float4 o;
        o.x = acc[i][0]; o.y = acc[i][1]; o.z = acc[i][2]; o.w = acc[i][3];
        *(float4*)&xh[(size_t)row * 256 + c0 + tc * 4] = o;
        float s1 = o.x * asw0 + o.y * asw1 + o.z * asw2 + o.w * asw3;
        float s2 = o.x * adw0 + o.y * adw1 + o.z * adw2 + o.w * adw3;
#pragma unroll
        for (int off = 1; off < 16; off <<= 1) {
            s1 += __shfl_xor(s1, off);
            s2 += __shfl_xor(s2, off);
        }
        if (tc == 0) {
            alS[row * 4 + head] = s1;
            alD[row * 4 + head] = s2;
        }
    }
}

// ---------------- per-destination two-phase softmax aggregation ----------------
// Block = one dst node; wave h = head h. Phase A: 64 lanes compute <=64 edge
// logits in parallel, butterfly max+sum. Phase B: independent weighted gather.

#define CH 64

__global__ __launch_bounds__(256) void attn_kernel(
        const int* __restrict__ rowptr, const int* __restrict__ csr,
        const float* __restrict__ xh, const float* __restrict__ alS,
        const float* __restrict__ alD, const float* __restrict__ bias,
        float* __restrict__ out, int do_relu) {
    __shared__ float wLds[CH][4];
    __shared__ int sLds[CH];
    int dst = blockIdx.x;
    int tid = threadIdx.x;
    int head = tid >> 6;
    int lane = tid & 63;
    int beg = rowptr[dst], end = rowptr[dst + 1];
    float ad = alD[dst * 4 + head];

    float m = -1e30f, den = 0.f, acc = 0.f;
    for (int c = beg; c < end; c += CH) {
        int n = end - c; if (n > CH) n = CH;
        // phase A
        float e = -1e30f;
        int s = 0;
        if (lane < n) {
            s = csr[c + lane];
            float t = alS[s * 4 + head] + ad;
            e = (t > 0.f) ? t : NEG_SLOPE * t;
        }
        if (head == 0 && lane < n) sLds[lane] = s;
        float mx = e;
#pragma unroll
        for (int off = 32; off >= 1; off >>= 1) mx = fmaxf(mx, __shfl_xor(mx, off));
        float mnew = fmaxf(m, mx);
        float p = (lane < n) ? __expf(e - mnew) : 0.f;
        wLds[lane][head] = p;
        float ps = p;
#pragma unroll
        for (int off = 32; off >= 1; off >>= 1) ps += __shfl_xor(ps, off);
        float sc = __expf(m - mnew);
        den = den * sc + ps;
        m = mnew;
        __syncthreads();
        // phase B: col = tid, independent iterations
        acc *= sc;
        for (int i = 0; i < n; i++) {
            int si = sLds[i];
            float w = wLds[i][head];
            acc += w * xh[(size_t)si * 256 + tid];
        }
        __syncthreads();
    }
    float o = acc / (den + 1e-16f) + bias[tid];
    if (do_relu) o = fmaxf(o, 0.f);
    out[(size_t)dst * 256 + tid] = o;
}

// ---------------------------------------------------------------------------

extern "C" void kernel_launch(void* const* d_in, const int* in_sizes, int n_in,
                              void* d_out, int out_size, void* d_ws, size_t ws_size,
                              hipStream_t stream) {
    const float* h0  = (const float*)d_in[0];
    const int*   ei1 = (const int*)d_in[1];
    const int*   ei2 = (const int*)d_in[2];
    const float* W10  = (const float*)d_in[3];
    const float* as10 = (const float*)d_in[4];
    const float* ad10 = (const float*)d_in[5];
    const float* b10  = (const float*)d_in[6];
    const float* W11  = (const float*)d_in[7];
    const float* as11 = (const float*)d_in[8];
    const float* ad11 = (const float*)d_in[9];
    const float* b11  = (const float*)d_in[10];
    const float* W20  = (const float*)d_in[11];
    const float* as20 = (const float*)d_in[12];
    const float* ad20 = (const float*)d_in[13];
    const float* b20  = (const float*)d_in[14];
    const float* W21  = (const float*)d_in[15];
    const float* as21 = (const float*)d_in[16];
    const float* ad21 = (const float*)d_in[17];
    const float* b21  = (const float*)d_in[18];

    const int N  = in_sizes[0] / 64;   // 8000 nodes
    const int E1 = in_sizes[1] / 2;
    const int E2 = in_sizes[2] / 2;

    char* base = (char*)d_ws;
    size_t off = 0;
    auto carve = [&](size_t bytes) -> void* {
        void* p = base + off;
        off += (bytes + 255) & ~(size_t)255;
        return p;
    };
    int* rowptr1 = (int*)carve((size_t)(N + 1) * 4);
    int* csr1    = (int*)carve((size_t)(E1 + N) * 4);
    int* rowptr2 = (int*)carve((size_t)(N + 1) * 4);
    int* csr2    = (int*)carve((size_t)(E2 + N) * 4);
    int* cnt     = (int*)carve((size_t)N * 4);
    float* xh    = (float*)carve((size_t)N * 256 * 4);
    float* hbuf  = (float*)carve((size_t)N * 256 * 4);
    float* alS   = (float*)carve((size_t)N * 4 * 4);
    float* alD   = (float*)carve((size_t)N * 4 * 4);
    (void)ws_size; (void)n_in;

    auto build_csr = [&](const int* ei, int E_raw, int* rowptr, int* csr) {
        int tot = E_raw + N;
        int blocks = (tot + 255) / 256;
        hipMemsetAsync(cnt, 0, (size_t)N * 4, stream);
        count_kernel<<<blocks, 256, 0, stream>>>(ei, E_raw, N, cnt);
        scan_kernel<<<1, 1024, 0, stream>>>(cnt, rowptr, N);
        hipMemsetAsync(cnt, 0, (size_t)N * 4, stream);
        scatter_kernel<<<blocks, 256, 0, stream>>>(ei, E_raw, N, rowptr, cnt, csr);
    };
    build_csr(ei1, E1, rowptr1, csr1);
    build_csr(ei2, E2, rowptr2, csr2);

    const dim3 gemmGrid((N + 63) / 64, 4);
    float* out0 = (float*)d_out;
    float* out1 = (float*)d_out + (size_t)N * 256;

    auto run_source = [&](const int* rowptr, const int* csr,
                          const float* W0, const float* aS0, const float* aD0, const float* bb0,
                          const float* W1, const float* aS1, const float* aD1, const float* bb1,
                          float* out) {
        gemm_alpha_kernel<<<gemmGrid, 256, 0, stream>>>(h0, W0, aS0, aD0, xh, alS, alD, 64, N);
        attn_kernel<<<N, 256, 0, stream>>>(rowptr, csr, xh, alS, alD, bb0, hbuf, 1);
        gemm_alpha_kernel<<<gemmGrid, 256, 0, stream>>>(hbuf, W1, aS1, aD1, xh, alS, alD, 256, N);
        attn_kernel<<<N, 256, 0, stream>>>(rowptr, csr, xh, alS, alD, bb1, out, 0);
    };
    run_source(rowptr1, csr1, W10, as10, ad10, b10, W11, as11, ad11, b11, out0);
    run_source(rowptr2, csr2, W20, as20, ad20, b20, W21, as21, ad21, b21, out1);
}

// Round 3
// 217.537 us; speedup vs baseline: 2.3671x; 1.2393x over previous
//
#include <hip/hip_runtime.h>
#include <hip/hip_fp16.h>

// ---------------------------------------------------------------------------
// MultiSourceGNNBlock: two independent 2-layer GAT stacks on shared input.
// R2: fp16 xh for the attention gather (halves L2/L3 traffic), both sources
// merged into single dispatches (gridDim.z / block-range), 6 kernels total.
// ---------------------------------------------------------------------------

#define NEG_SLOPE 0.2f

// ---------------- CSR build (both sources, one pass) ----------------

__global__ __launch_bounds__(256) void count_both_kernel(
        const int* __restrict__ ei1, int E1,
        const int* __restrict__ ei2, int E2,
        int N, int* __restrict__ cnt /* [2N] */) {
    int i = blockIdx.x * 256 + threadIdx.x;
    int tot1 = E1 + N;
    int tot2 = E2 + N;
    if (i >= tot1 + tot2) return;
    int s, j; const int* ei; int E;
    if (i < tot1) { s = 0; j = i;        ei = ei1; E = E1; }
    else          { s = 1; j = i - tot1; ei = ei2; E = E2; }
    int dst = (j < E) ? ei[E + j] : (j - E);   // row1 = dst; tail = self-loops
    atomicAdd(&cnt[s * N + dst], 1);
}

// one block per source; single-pass exclusive scan for n <= 8192
__global__ __launch_bounds__(1024) void scan_kernel(
        const int* __restrict__ cnt, int* __restrict__ rp1,
        int* __restrict__ rp2, int n) {
    __shared__ int buf[1024];
    const int* c = cnt + blockIdx.x * n;
    int* rowptr = (blockIdx.x == 0) ? rp1 : rp2;
    int tid = threadIdx.x;
    int v[8];
    int local = 0;
    int base = tid * 8;
#pragma unroll
    for (int j = 0; j < 8; j++) {
        int i = base + j;
        int x = (i < n) ? c[i] : 0;
        v[j] = local;
        local += x;
    }
    buf[tid] = local;
    __syncthreads();
    for (int off = 1; off < 1024; off <<= 1) {
        int t = (tid >= off) ? buf[tid - off] : 0;
        __syncthreads();
        buf[tid] += t;
        __syncthreads();
    }
    int prev = (tid == 0) ? 0 : buf[tid - 1];
#pragma unroll
    for (int j = 0; j < 8; j++) {
        int i = base + j;
        if (i < n) rowptr[i] = prev + v[j];
    }
    if (tid == 1023) rowptr[n] = buf[1023];
}

__global__ __launch_bounds__(256) void scatter_both_kernel(
        const int* __restrict__ ei1, int E1,
        const int* __restrict__ ei2, int E2, int N,
        const int* __restrict__ rp1, const int* __restrict__ rp2,
        int* __restrict__ cur /* [2N] */,
        int* __restrict__ csr1, int* __restrict__ csr2) {
    int i = blockIdx.x * 256 + threadIdx.x;
    int tot1 = E1 + N;
    int tot2 = E2 + N;
    if (i >= tot1 + tot2) return;
    int s, j; const int* ei; int E;
    if (i < tot1) { s = 0; j = i;        ei = ei1; E = E1; }
    else          { s = 1; j = i - tot1; ei = ei2; E = E2; }
    int src, dst;
    if (j < E) { src = ei[j]; dst = ei[E + j]; }
    else       { src = dst = j - E; }
    const int* rp = s ? rp2 : rp1;
    int* csr = s ? csr2 : csr1;
    int pos = rp[dst] + atomicAdd(&cur[s * N + dst], 1);
    csr[pos] = src;
}

// ---------------- tiled GEMM (xh = h @ W, fp16 out) + fused alpha ----------------
// Block tile 64 rows x 64 cols; blockIdx.y == head; blockIdx.z == source.

#define KT 16

struct GemmArgs {
    const float *h0, *h1, *W0, *W1, *as0, *as1, *ad0, *ad1;
    __half *xh0, *xh1;
    float *alS0, *alS1, *alD0, *alD1;
    int K, M;
};

__global__ __launch_bounds__(256) void gemm_alpha_kernel(GemmArgs g) {
    __shared__ float As[KT][64];
    __shared__ float Bs[KT][64];
    int s = blockIdx.z;
    const float* h     = s ? g.h1  : g.h0;
    const float* W     = s ? g.W1  : g.W0;
    const float* a_src = s ? g.as1 : g.as0;
    const float* a_dst = s ? g.ad1 : g.ad0;
    __half* xh = s ? g.xh1 : g.xh0;
    float* alS = s ? g.alS1 : g.alS0;
    float* alD = s ? g.alD1 : g.alD0;
    const int K = g.K;

    int tid = threadIdx.x;
    int row0 = blockIdx.x * 64;
    int head = blockIdx.y;
    int c0 = head * 64;
    int tc = tid & 15, tr = tid >> 4;

    float acc[4][4] = {};

    int arow = tid >> 2, aseg = tid & 3;   // A stage: 64 rows x (4 x float4) of KT
    int brow = tid >> 4, bseg = tid & 15;  // B stage: KT rows x (16 x float4) of 64

    const float* hA = &h[(size_t)(row0 + arow) * K + aseg * 4];
    const float* wB = &W[(size_t)brow * 256 + c0 + bseg * 4];

    for (int k0 = 0; k0 < K; k0 += KT) {
        float4 av = *(const float4*)(hA + k0);
        float4 bv = *(const float4*)(wB + (size_t)k0 * 256);
        __syncthreads();
        As[aseg * 4 + 0][arow] = av.x;
        As[aseg * 4 + 1][arow] = av.y;
        As[aseg * 4 + 2][arow] = av.z;
        As[aseg * 4 + 3][arow] = av.w;
        *(float4*)&Bs[brow][bseg * 4] = bv;
        __syncthreads();
#pragma unroll
        for (int kk = 0; kk < KT; kk++) {
            float4 a = *(const float4*)&As[kk][tr * 4];
            float4 b = *(const float4*)&Bs[kk][tc * 4];
            acc[0][0] += a.x * b.x; acc[0][1] += a.x * b.y; acc[0][2] += a.x * b.z; acc[0][3] += a.x * b.w;
            acc[1][0] += a.y * b.x; acc[1][1] += a.y * b.y; acc[1][2] += a.y * b.z; acc[1][3] += a.y * b.w;
            acc[2][0] += a.z * b.x; acc[2][1] += a.z * b.y; acc[2][2] += a.z * b.z; acc[2][3] += a.z * b.w;
            acc[3][0] += a.w * b.x; acc[3][1] += a.w * b.y; acc[3][2] += a.w * b.z; acc[3][3] += a.w * b.w;
        }
    }

    float asw0 = a_src[c0 + tc * 4 + 0], asw1 = a_src[c0 + tc * 4 + 1];
    float asw2 = a_src[c0 + tc * 4 + 2], asw3 = a_src[c0 + tc * 4 + 3];
    float adw0 = a_dst[c0 + tc * 4 + 0], adw1 = a_dst[c0 + tc * 4 + 1];
    float adw2 = a_dst[c0 + tc * 4 + 2], adw3 = a_dst[c0 + tc * 4 + 3];

#pragma unroll
    for (int i = 0; i < 4; i++) {
        int row = row0 + tr * 4 + i;
        float4 o;
        o.x = acc[i][0]; o.y = acc[i][1]; o.z = acc[i][2]; o.w = acc[i][3];
        __half2 p01 = __floats2half2_rn(o.x, o.y);
        __half2 p23 = __floats2half2_rn(o.z, o.w);
        __half2* dst2 = (__half2*)&xh[(size_t)row * 256 + c0 + tc * 4];
        dst2[0] = p01;
        dst2[1] = p23;
        float s1 = o.x * asw0 + o.y * asw1 + o.z * asw2 + o.w * asw3;
        float s2 = o.x * adw0 + o.y * adw1 + o.z * adw2 + o.w * adw3;
#pragma unroll
        for (int off = 1; off < 16; off <<= 1) {
            s1 += __shfl_xor(s1, off);
            s2 += __shfl_xor(s2, off);
        }
        if (tc == 0) {
            alS[row * 4 + head] = s1;
            alD[row * 4 + head] = s2;
        }
    }
}

// ---------------- per-destination two-phase softmax aggregation ----------------
// blockIdx.x in [0,2N): source = blockIdx.x >= N. Wave h = head h.

#define CH 64

struct AttnArgs {
    const int *rp0, *rp1, *csr0, *csr1;
    const __half *xh0, *xh1;
    const float *alS0, *alS1, *alD0, *alD1, *b0, *b1;
    float *out0, *out1;
    int N, do_relu;
};

__global__ __launch_bounds__(256) void attn_kernel(AttnArgs a) {
    __shared__ float wLds[CH][4];
    __shared__ int sLds[CH];
    int bid = blockIdx.x;
    int s = (bid >= a.N) ? 1 : 0;
    int dst = bid - s * a.N;
    const int* rowptr  = s ? a.rp1  : a.rp0;
    const int* csr     = s ? a.csr1 : a.csr0;
    const __half* xh   = s ? a.xh1  : a.xh0;
    const float* alS   = s ? a.alS1 : a.alS0;
    const float* alD   = s ? a.alD1 : a.alD0;
    const float* bias  = s ? a.b1   : a.b0;
    float* out         = s ? a.out1 : a.out0;

    int tid = threadIdx.x;
    int head = tid >> 6;
    int lane = tid & 63;
    int beg = rowptr[dst], end = rowptr[dst + 1];
    float ad = alD[dst * 4 + head];

    float m = -1e30f, den = 0.f, acc = 0.f;
    for (int c = beg; c < end; c += CH) {
        int n = end - c; if (n > CH) n = CH;
        // phase A: wave-parallel logits
        float e = -1e30f;
        int src = 0;
        if (lane < n) {
            src = csr[c + lane];
            float t = alS[src * 4 + head] + ad;
            e = (t > 0.f) ? t : NEG_SLOPE * t;
        }
        if (head == 0 && lane < n) sLds[lane] = src;
        float mx = e;
#pragma unroll
        for (int off = 32; off >= 1; off >>= 1) mx = fmaxf(mx, __shfl_xor(mx, off));
        float mnew = fmaxf(m, mx);
        float p = (lane < n) ? __expf(e - mnew) : 0.f;
        wLds[lane][head] = p;
        float ps = p;
#pragma unroll
        for (int off = 32; off >= 1; off >>= 1) ps += __shfl_xor(ps, off);
        float sc = __expf(m - mnew);
        den = den * sc + ps;
        m = mnew;
        __syncthreads();
        // phase B: weighted gather, col = tid
        acc *= sc;
#pragma unroll 4
        for (int i = 0; i < n; i++) {
            int si = sLds[i];
            float w = wLds[i][head];
            acc += w * __half2float(xh[(size_t)si * 256 + tid]);
        }
        __syncthreads();
    }
    float o = acc / (den + 1e-16f) + bias[tid];
    if (a.do_relu) o = fmaxf(o, 0.f);
    out[(size_t)dst * 256 + tid] = o;
}

// ---------------------------------------------------------------------------

extern "C" void kernel_launch(void* const* d_in, const int* in_sizes, int n_in,
                              void* d_out, int out_size, void* d_ws, size_t ws_size,
                              hipStream_t stream) {
    const float* h0  = (const float*)d_in[0];
    const int*   ei1 = (const int*)d_in[1];
    const int*   ei2 = (const int*)d_in[2];
    const float* W10  = (const float*)d_in[3];
    const float* as10 = (const float*)d_in[4];
    const float* ad10 = (const float*)d_in[5];
    const float* b10  = (const float*)d_in[6];
    const float* W11  = (const float*)d_in[7];
    const float* as11 = (const float*)d_in[8];
    const float* ad11 = (const float*)d_in[9];
    const float* b11  = (const float*)d_in[10];
    const float* W20  = (const float*)d_in[11];
    const float* as20 = (const float*)d_in[12];
    const float* ad20 = (const float*)d_in[13];
    const float* b20  = (const float*)d_in[14];
    const float* W21  = (const float*)d_in[15];
    const float* as21 = (const float*)d_in[16];
    const float* ad21 = (const float*)d_in[17];
    const float* b21  = (const float*)d_in[18];

    const int N  = in_sizes[0] / 64;   // 8000 nodes
    const int E1 = in_sizes[1] / 2;
    const int E2 = in_sizes[2] / 2;

    char* base = (char*)d_ws;
    size_t off = 0;
    auto carve = [&](size_t bytes) -> void* {
        void* p = base + off;
        off += (bytes + 255) & ~(size_t)255;
        return p;
    };
    int* rowptr1 = (int*)carve((size_t)(N + 1) * 4);
    int* csr1    = (int*)carve((size_t)(E1 + N) * 4);
    int* rowptr2 = (int*)carve((size_t)(N + 1) * 4);
    int* csr2    = (int*)carve((size_t)(E2 + N) * 4);
    int* cnt     = (int*)carve((size_t)2 * N * 4);
    __half* xh1  = (__half*)carve((size_t)N * 256 * 2);
    __half* xh2  = (__half*)carve((size_t)N * 256 * 2);
    float* hbuf1 = (float*)carve((size_t)N * 256 * 4);
    float* hbuf2 = (float*)carve((size_t)N * 256 * 4);
    float* alS1  = (float*)carve((size_t)N * 4 * 4);
    float* alD1  = (float*)carve((size_t)N * 4 * 4);
    float* alS2  = (float*)carve((size_t)N * 4 * 4);
    float* alD2  = (float*)carve((size_t)N * 4 * 4);
    (void)ws_size; (void)n_in;

    float* out0 = (float*)d_out;
    float* out1 = (float*)d_out + (size_t)N * 256;

    // ---- CSR build (both sources) ----
    int tot = (E1 + N) + (E2 + N);
    int cblocks = (tot + 255) / 256;
    hipMemsetAsync(cnt, 0, (size_t)2 * N * 4, stream);
    count_both_kernel<<<cblocks, 256, 0, stream>>>(ei1, E1, ei2, E2, N, cnt);
    scan_kernel<<<2, 1024, 0, stream>>>(cnt, rowptr1, rowptr2, N);
    hipMemsetAsync(cnt, 0, (size_t)2 * N * 4, stream);
    scatter_both_kernel<<<cblocks, 256, 0, stream>>>(ei1, E1, ei2, E2, N,
                                                     rowptr1, rowptr2, cnt, csr1, csr2);

    const dim3 gemmGrid((N + 63) / 64, 4, 2);
    const dim3 attnGrid(2 * N);

    GemmArgs g0 = { h0, h0, W10, W20, as10, as20, ad10, ad20,
                    xh1, xh2, alS1, alS2, alD1, alD2, 64, N };
    AttnArgs a0 = { rowptr1, rowptr2, csr1, csr2, xh1, xh2,
                    alS1, alS2, alD1, alD2, b10, b20, hbuf1, hbuf2, N, 1 };
    GemmArgs g1 = { hbuf1, hbuf2, W11, W21, as11, as21, ad11, ad21,
                    xh1, xh2, alS1, alS2, alD1, alD2, 256, N };
    AttnArgs a1 = { rowptr1, rowptr2, csr1, csr2, xh1, xh2,
                    alS1, alS2, alD1, alD2, b11, b21, out0, out1, N, 0 };

    gemm_alpha_kernel<<<gemmGrid, 256, 0, stream>>>(g0);
    attn_kernel<<<attnGrid, 256, 0, stream>>>(a0);
    gemm_alpha_kernel<<<gemmGrid, 256, 0, stream>>>(g1);
    attn_kernel<<<attnGrid, 256, 0, stream>>>(a1);
}